// Round 7
// baseline (523.918 us; speedup 1.0000x reference)
//
#include <hip/hip_runtime.h>
#include <math.h>

// NoiScaleModule: B=128, C=32(seq), S=512(d_model), EMB=256, NHEAD=8, DFF=2048
// All tensors FLOAT32. Outputs concat flat: res[2M], down_x[2M], fa[2M], up[2M]
//
// R10: cattn2 512-thread. 560->557.
// R11: XCD-chunked blockIdx swizzle on all GEMMs (T1). 557->520.
// R12: all-128 tiles — REGRESSION (551): grids collapsed to 1 block/CU.
// R13: BK=64 K-step — NEUTRAL (520): barrier count wasn't the limiter.
// R14: SELECTIVE retile where grid stays >=2 blocks/CU: lin1 128x128 (1024 blk),
//      lin2/out 128x64 (512 blk); freq/up/qkv stay 64-class. wa/wm emit bf16
//      hi/lo directly (kills 2 cvt_hilo dispatches).

#define NROW 4096
#define NOUT 2097152

typedef __attribute__((ext_vector_type(8))) short short8;
typedef __attribute__((ext_vector_type(4))) float floatx4;

__device__ __forceinline__ unsigned short f2bf(float f) {
    union { float f; unsigned u; } v; v.f = f;
    return (unsigned short)((v.u + 0x7fffu + ((v.u >> 16) & 1u)) >> 16);
}
__device__ __forceinline__ float bf2f(unsigned short h) {
    union { unsigned u; float f; } v; v.u = ((unsigned)h) << 16;
    return v.f;
}

__device__ __forceinline__ void gload16(const unsigned short* g, unsigned short* l) {
    __builtin_amdgcn_global_load_lds((const __attribute__((address_space(1))) void*)g,
                                     (__attribute__((address_space(3))) void*)l, 16, 0, 0);
}

// XCD-chunked swizzle (T1): consecutive dispatch ids round-robin XCDs; remap so
// each XCD gets a contiguous chunk of logical tiles (requires nwg % 8 == 0).
__device__ __forceinline__ void xcd_swizzle(int& bx, int& by, int& bz) {
    const int gx = gridDim.x, gy = gridDim.y;
    const int nwg = gx * gy * gridDim.z;
    int b = (bz * gy + by) * gx + bx;
    const int chunk = nwg >> 3;
    const int lb = (b & 7) * chunk + (b >> 3);
    bx = lb % gx;
    const int rem = lb / gx;
    by = rem % gy;
    bz = rem / gy;
}

// ---------------- prep: cos/sin tables tab[n][k], n<512, k<256 ----------------
__global__ __launch_bounds__(256) void tab_kernel(float* __restrict__ tabC, float* __restrict__ tabS)
{
    int n = blockIdx.x, k = threadIdx.x;
    int m = (n * k) & 511;
    float th = (float)m * 0.01227184630308513f;  // 2*pi/512
    float s, c; sincosf(th, &s, &c);
    tabC[n * 256 + k] = c;
    tabS[n * 256 + k] = s;
}

// Wa emitted directly as bf16 hi/lo (R14)
__global__ __launch_bounds__(256) void wa_kernel(const float* __restrict__ l1_re, const float* __restrict__ l1_im,
                                                 const float* __restrict__ tabC, const float* __restrict__ tabS,
                                                 unsigned short* __restrict__ Wh, unsigned short* __restrict__ Wl)
{
    int n  = blockIdx.x;
    int ep = blockIdx.y * 256 + threadIdx.x;
    const float inv = 0.04419417382415922f;  // 1/sqrt(512)
    float acc = 0.f;
    if (ep < 256) {
        for (int k = 0; k < 128; ++k) {
            float c = tabC[n * 256 + k], s = tabS[n * 256 + k];
            acc += c * l1_re[k * 256 + ep] + s * l1_im[k * 256 + ep];
        }
    } else {
        int e = ep - 256;
        for (int k = 0; k < 128; ++k) {
            float c = tabC[n * 256 + k], s = tabS[n * 256 + k];
            acc += c * l1_im[k * 256 + e] - s * l1_re[k * 256 + e];
        }
    }
    float v = acc * inv;
    size_t idx = (size_t)ep * 512 + n;
    unsigned short h = f2bf(v);
    Wh[idx] = h;
    Wl[idx] = f2bf(v - bf2f(h));
}

// Wm emitted directly as bf16 hi/lo (R14)
__global__ __launch_bounds__(256) void wm_kernel(const float* __restrict__ lc_w,
                                                 const float* __restrict__ tabC, const float* __restrict__ tabS,
                                                 unsigned short* __restrict__ Wh, unsigned short* __restrict__ Wl)
{
    __shared__ float lw[512];
    int s  = blockIdx.x;
    int kk = blockIdx.y * 256 + threadIdx.x;
    for (int i = threadIdx.x; i < 512; i += 256) lw[i] = lc_w[s * 512 + i];
    __syncthreads();
    const float inv = 0.04419417382415922f;
    float acc = 0.f;
    if (kk < 256) {
        int k = kk;
        for (int n = 0; n < 512; ++n) acc += tabC[n * 256 + k] * lw[n];
        acc *= (k == 0) ? inv : 2.f * inv;
    } else {
        int k = kk - 256;
        if (k == 0) acc = 0.f;
        else {
            for (int n = 0; n < 512; ++n) acc += tabS[n * 256 + k] * lw[n];
            acc *= -2.f * inv;
        }
    }
    size_t idx = (size_t)s * 512 + kk;
    unsigned short h = f2bf(acc);
    Wh[idx] = h;
    Wl[idx] = f2bf(acc - bf2f(h));
}

// LB[0:512] = [lb1_re|lb1_im]
__global__ __launch_bounds__(256) void lbpack_kernel(const float* __restrict__ re, const float* __restrict__ im,
                                                     float* __restrict__ out)
{
    int i = threadIdx.x + blockIdx.x * 256;
    if (i < 512) out[i] = (i < 256) ? re[i] : im[i - 256];
}

// convert all 10 weight matrices to bf16 into one arena
__global__ __launch_bounds__(256) void wcvt_kernel(
    const float* s0, const float* s1, const float* s2, const float* s3, const float* s4,
    const float* s5, const float* s6, const float* s7, const float* s8, const float* s9,
    unsigned short* __restrict__ o)
{
    int i = blockIdx.x * 256 + threadIdx.x;
    if (i >= 6815744) return;
    const float* s; int off;
    if (i < 3145728) {
        if (i < 1048576) { if (i < 786432) { s = s0; off = 0; } else { s = s1; off = 786432; } }
        else             { if (i < 2097152) { s = s2; off = 1048576; } else { s = s3; off = 2097152; } }
    } else {
        if (i < 5242880) {
            if (i < 3932160) { s = s4; off = 3145728; }
            else if (i < 4194304) { s = s5; off = 3932160; }
            else { s = s6; off = 4194304; }
        } else {
            if (i < 6291456) { s = s7; off = 5242880; }
            else if (i < 6553600) { s = s8; off = 6291456; }
            else { s = s9; off = 6553600; }
        }
    }
    o[i] = f2bf(s[i - off]);
}

__global__ __launch_bounds__(256) void cvt_lo_kernel(const float* __restrict__ a, const unsigned short* __restrict__ hi,
                                                     unsigned short* __restrict__ lo, int n)
{
    for (int i = blockIdx.x * 256 + threadIdx.x; i < n; i += gridDim.x * 256)
        lo[i] = f2bf(a[i] - bf2f(hi[i]));
}

// x -> hi/lo bf16 + f32 copy (down_x output)
__global__ __launch_bounds__(256) void xsplit_kernel(const float* __restrict__ a, unsigned short* __restrict__ hi,
                                                     unsigned short* __restrict__ lo, float* __restrict__ cp, int n)
{
    for (int i = blockIdx.x * 256 + threadIdx.x; i < n; i += gridDim.x * 256) {
        float v = a[i];
        unsigned short h = f2bf(v);
        hi[i] = h;
        lo[i] = f2bf(v - bf2f(h));
        cp[i] = v;
    }
}

// ---------------- MFMA GEMM: C[M,N] = A[M,K](bf16) @ W[N,K](bf16)^T + bias ----------------
// TM x TN tile, BK=64 (2x32 sub-chunks, one sync pair per 64-K), 4 waves (2x2),
// single LDS buffer, XCD-swizzled tiles.
template <int TM, int TN, int ACT, int WF, int WBF>
__global__ __launch_bounds__(256) void gemm_mfma(
    const unsigned short* __restrict__ A, const unsigned short* __restrict__ W,
    const float* __restrict__ bias, float* __restrict__ Cf,
    unsigned short* __restrict__ Cb, int N, int K)
{
    constexpr int MI = TM / 32, NJ = TN / 32;
    constexpr int ARW = TM / 4, BRW = TN / 4;
    __shared__ unsigned short As[2][TM * 32];
    __shared__ unsigned short Bs[2][TN * 32];
    const int tid = threadIdx.x;
    const int wave = tid >> 6, lane = tid & 63;
    int bx = blockIdx.x, by = blockIdx.y, bz = blockIdx.z;
    xcd_swizzle(bx, by, bz);
    const int m0 = by * TM, n0 = bx * TN;
    const int sr = lane >> 2, sc = (lane & 3) * 8;
    const unsigned short* aS = A + (size_t)(m0 + wave * ARW + sr) * K + sc;
    const unsigned short* wS = W + (size_t)(n0 + wave * BRW + sr) * K + sc;
    const int wm = (wave >> 1) * (TM / 2), wn = (wave & 1) * (TN / 2);
    const int fr = lane & 15, fko = (lane >> 4) * 8;

    floatx4 acc[MI][NJ];
#pragma unroll
    for (int i = 0; i < MI; ++i)
#pragma unroll
        for (int j = 0; j < NJ; ++j) acc[i][j] = (floatx4){0.f, 0.f, 0.f, 0.f};

    for (int k0 = 0; k0 < K; k0 += 64) {
#pragma unroll
        for (int h = 0; h < 2; ++h) {
#pragma unroll
            for (int c = 0; c < ARW / 16; ++c)
                gload16(aS + (size_t)(16 * c) * K + k0 + 32 * h, &As[h][(wave * ARW + 16 * c) * 32]);
#pragma unroll
            for (int c = 0; c < BRW / 16; ++c)
                gload16(wS + (size_t)(16 * c) * K + k0 + 32 * h, &Bs[h][(wave * BRW + 16 * c) * 32]);
        }
        __syncthreads();
#pragma unroll
        for (int h = 0; h < 2; ++h) {
            short8 af[MI], bfr[NJ];
#pragma unroll
            for (int i = 0; i < MI; ++i) af[i] = *(const short8*)&As[h][(wm + i * 16 + fr) * 32 + fko];
#pragma unroll
            for (int j = 0; j < NJ; ++j) bfr[j] = *(const short8*)&Bs[h][(wn + j * 16 + fr) * 32 + fko];
#pragma unroll
            for (int i = 0; i < MI; ++i)
#pragma unroll
                for (int j = 0; j < NJ; ++j)
                    acc[i][j] = __builtin_amdgcn_mfma_f32_16x16x32_bf16(af[i], bfr[j], acc[i][j], 0, 0, 0);
        }
        __syncthreads();
    }
    const int r0 = m0 + wm + (lane >> 4) * 4;
#pragma unroll
    for (int i = 0; i < MI; ++i) {
#pragma unroll
        for (int j = 0; j < NJ; ++j) {
            int n = n0 + wn + j * 16 + fr;
            float bv = bias[n];
#pragma unroll
            for (int r = 0; r < 4; ++r) {
                int m = r0 + i * 16 + r;
                size_t idx = (size_t)m * N + n;
                float v = acc[i][j][r] + bv;
                if (ACT) v = fmaxf(v, 0.f);
                if (WF) Cf[idx] = v;
                if (WBF) Cb[idx] = f2bf(v);
            }
        }
    }
}

// ---------------- dual-branch GEMM: z=0 -> (A0,W0,b0)->out0, z=1 -> (A1,W1,b1)->out1 ------
template <int TM, int TN, int ACT, int WBF>
__global__ __launch_bounds__(256) void gemm_dual(
    const unsigned short* __restrict__ A0, const unsigned short* __restrict__ A1,
    const unsigned short* __restrict__ W0, const unsigned short* __restrict__ W1,
    const float* __restrict__ b0, const float* __restrict__ b1,
    float* __restrict__ C0, float* __restrict__ C1,
    unsigned short* __restrict__ D0, unsigned short* __restrict__ D1, int N, int K)
{
    constexpr int MI = TM / 32, NJ = TN / 32;
    constexpr int ARW = TM / 4, BRW = TN / 4;
    __shared__ unsigned short As[2][TM * 32];
    __shared__ unsigned short Bs[2][TN * 32];
    const int tid = threadIdx.x;
    const int wave = tid >> 6, lane = tid & 63;
    int bx = blockIdx.x, by = blockIdx.y, bz = blockIdx.z;
    xcd_swizzle(bx, by, bz);
    const int m0 = by * TM, n0 = bx * TN;
    const int z = bz;
    const unsigned short* A = z ? A1 : A0;
    const unsigned short* W = z ? W1 : W0;
    const float* bias = z ? b1 : b0;
    float* Cf = z ? C1 : C0;
    unsigned short* Cb = z ? D1 : D0;
    const int sr = lane >> 2, sc = (lane & 3) * 8;
    const unsigned short* aS = A + (size_t)(m0 + wave * ARW + sr) * K + sc;
    const unsigned short* wS = W + (size_t)(n0 + wave * BRW + sr) * K + sc;
    const int wm = (wave >> 1) * (TM / 2), wn = (wave & 1) * (TN / 2);
    const int fr = lane & 15, fko = (lane >> 4) * 8;

    floatx4 acc[MI][NJ];
#pragma unroll
    for (int i = 0; i < MI; ++i)
#pragma unroll
        for (int j = 0; j < NJ; ++j) acc[i][j] = (floatx4){0.f, 0.f, 0.f, 0.f};

    for (int k0 = 0; k0 < K; k0 += 64) {
#pragma unroll
        for (int h = 0; h < 2; ++h) {
#pragma unroll
            for (int c = 0; c < ARW / 16; ++c)
                gload16(aS + (size_t)(16 * c) * K + k0 + 32 * h, &As[h][(wave * ARW + 16 * c) * 32]);
#pragma unroll
            for (int c = 0; c < BRW / 16; ++c)
                gload16(wS + (size_t)(16 * c) * K + k0 + 32 * h, &Bs[h][(wave * BRW + 16 * c) * 32]);
        }
        __syncthreads();
#pragma unroll
        for (int h = 0; h < 2; ++h) {
            short8 af[MI], bfr[NJ];
#pragma unroll
            for (int i = 0; i < MI; ++i) af[i] = *(const short8*)&As[h][(wm + i * 16 + fr) * 32 + fko];
#pragma unroll
            for (int j = 0; j < NJ; ++j) bfr[j] = *(const short8*)&Bs[h][(wn + j * 16 + fr) * 32 + fko];
#pragma unroll
            for (int i = 0; i < MI; ++i)
#pragma unroll
                for (int j = 0; j < NJ; ++j)
                    acc[i][j] = __builtin_amdgcn_mfma_f32_16x16x32_bf16(af[i], bfr[j], acc[i][j], 0, 0, 0);
        }
        __syncthreads();
    }
    const int r0 = m0 + wm + (lane >> 4) * 4;
#pragma unroll
    for (int i = 0; i < MI; ++i) {
#pragma unroll
        for (int j = 0; j < NJ; ++j) {
            int n = n0 + wn + j * 16 + fr;
            float bv = bias[n];
#pragma unroll
            for (int r = 0; r < 4; ++r) {
                int m = r0 + i * 16 + r;
                size_t idx = (size_t)m * N + n;
                float v = acc[i][j][r] + bv;
                if (ACT) v = fmaxf(v, 0.f);
                if (WBF) Cb[idx] = f2bf(v);
                else     Cf[idx] = v;
            }
        }
    }
}

// ---------------- fused hi/lo 3-product MFMA GEMM (BK=64, single-buffer) ----------------
template <int TM, int TN, int ACT, int WCOPY, int WHILO>
__global__ __launch_bounds__(256) void gemm_mfma3(
    const unsigned short* __restrict__ Ah, const unsigned short* __restrict__ Al,
    const unsigned short* __restrict__ Wh, const unsigned short* __restrict__ Wl,
    const float* __restrict__ bias, float* __restrict__ Cf, float* __restrict__ Ccopy,
    unsigned short* __restrict__ Hh, unsigned short* __restrict__ Hl, int N, int K)
{
    constexpr int MI = TM / 32, NJ = TN / 32;
    constexpr int ARW = TM / 4, BRW = TN / 4;
    __shared__ unsigned short Ash[2][TM * 32];
    __shared__ unsigned short Asl[2][TM * 32];
    __shared__ unsigned short Bsh[2][TN * 32];
    __shared__ unsigned short Bsl[2][TN * 32];
    const int tid = threadIdx.x;
    const int wave = tid >> 6, lane = tid & 63;
    int bx = blockIdx.x, by = blockIdx.y, bz = blockIdx.z;
    xcd_swizzle(bx, by, bz);
    const int m0 = by * TM, n0 = bx * TN;
    const int sr = lane >> 2, sc = (lane & 3) * 8;
    const size_t aoff = (size_t)(m0 + wave * ARW + sr) * K + sc;
    const size_t woff = (size_t)(n0 + wave * BRW + sr) * K + sc;
    const int wm = (wave >> 1) * (TM / 2), wn = (wave & 1) * (TN / 2);
    const int fr = lane & 15, fko = (lane >> 4) * 8;

    floatx4 acc[MI][NJ];
#pragma unroll
    for (int i = 0; i < MI; ++i)
#pragma unroll
        for (int j = 0; j < NJ; ++j) acc[i][j] = (floatx4){0.f, 0.f, 0.f, 0.f};

    for (int k0 = 0; k0 < K; k0 += 64) {
#pragma unroll
        for (int h = 0; h < 2; ++h) {
#pragma unroll
            for (int c = 0; c < ARW / 16; ++c) {
                gload16(Ah + aoff + (size_t)(16 * c) * K + k0 + 32 * h, &Ash[h][(wave * ARW + 16 * c) * 32]);
                gload16(Al + aoff + (size_t)(16 * c) * K + k0 + 32 * h, &Asl[h][(wave * ARW + 16 * c) * 32]);
            }
#pragma unroll
            for (int c = 0; c < BRW / 16; ++c) {
                gload16(Wh + woff + (size_t)(16 * c) * K + k0 + 32 * h, &Bsh[h][(wave * BRW + 16 * c) * 32]);
                gload16(Wl + woff + (size_t)(16 * c) * K + k0 + 32 * h, &Bsl[h][(wave * BRW + 16 * c) * 32]);
            }
        }
        __syncthreads();
#pragma unroll
        for (int h = 0; h < 2; ++h) {
            short8 ah[MI], al[MI], bh[NJ], bl[NJ];
#pragma unroll
            for (int i = 0; i < MI; ++i) {
                ah[i] = *(const short8*)&Ash[h][(wm + i * 16 + fr) * 32 + fko];
                al[i] = *(const short8*)&Asl[h][(wm + i * 16 + fr) * 32 + fko];
            }
#pragma unroll
            for (int j = 0; j < NJ; ++j) {
                bh[j] = *(const short8*)&Bsh[h][(wn + j * 16 + fr) * 32 + fko];
                bl[j] = *(const short8*)&Bsl[h][(wn + j * 16 + fr) * 32 + fko];
            }
#pragma unroll
            for (int i = 0; i < MI; ++i)
#pragma unroll
                for (int j = 0; j < NJ; ++j) {
                    acc[i][j] = __builtin_amdgcn_mfma_f32_16x16x32_bf16(al[i], bh[j], acc[i][j], 0, 0, 0);
                    acc[i][j] = __builtin_amdgcn_mfma_f32_16x16x32_bf16(ah[i], bl[j], acc[i][j], 0, 0, 0);
                    acc[i][j] = __builtin_amdgcn_mfma_f32_16x16x32_bf16(ah[i], bh[j], acc[i][j], 0, 0, 0);
                }
        }
        __syncthreads();
    }
    const int r0 = m0 + wm + (lane >> 4) * 4;
#pragma unroll
    for (int i = 0; i < MI; ++i) {
#pragma unroll
        for (int j = 0; j < NJ; ++j) {
            int n = n0 + wn + j * 16 + fr;
            float bv = bias[n];
#pragma unroll
            for (int r = 0; r < 4; ++r) {
                int m = r0 + i * 16 + r;
                size_t idx = (size_t)m * N + n;
                float v = acc[i][j][r] + bv;
                if (ACT) v = fmaxf(v, 0.f);
                Cf[idx] = v;
                if (WCOPY) Ccopy[idx] = v;
                if (WHILO) {
                    unsigned short h = f2bf(v);
                    Hh[idx] = h;
                    Hl[idx] = f2bf(v - bf2f(h));
                }
            }
        }
    }
}

// ---------------- TEL attention, DUAL: blocks [0,1024) = r (f32 qkv), [1024,2048) = t ----
__global__ __launch_bounds__(256) void attn_dual_kernel(const float* __restrict__ qkvF,
                                                        const unsigned short* __restrict__ qkvB,
                                                        unsigned short* __restrict__ outR,
                                                        unsigned short* __restrict__ outT)
{
    const int isT = blockIdx.x >> 10;
    const int bid = blockIdx.x & 1023;
    const int b = bid >> 3;
    const int h = bid & 7;
    __shared__ float qs[32][65], ks[32][65], vs[32][65];
    __shared__ float ps[32][33];
    const int tid = threadIdx.x;
    if (isT) {
        for (int i = tid; i < 2048; i += 256) {
            int s = i >> 6, d = i & 63;
            size_t base = ((size_t)(b * 32 + s)) * 1536 + h * 64 + d;
            qs[s][d] = bf2f(qkvB[base]);
            ks[s][d] = bf2f(qkvB[base + 512]);
            vs[s][d] = bf2f(qkvB[base + 1024]);
        }
    } else {
        for (int i = tid; i < 2048; i += 256) {
            int s = i >> 6, d = i & 63;
            size_t base = ((size_t)(b * 32 + s)) * 1536 + h * 64 + d;
            qs[s][d] = qkvF[base];
            ks[s][d] = qkvF[base + 512];
            vs[s][d] = qkvF[base + 1024];
        }
    }
    __syncthreads();
    for (int i = tid; i < 1024; i += 256) {
        int si = i >> 5, sj = i & 31;
        float acc = 0.f;
#pragma unroll 8
        for (int d = 0; d < 64; ++d) acc += qs[si][d] * ks[sj][d];
        ps[si][sj] = acc * 0.125f;
    }
    __syncthreads();
    if (tid < 32) {
        float mx = -1e30f;
        for (int j = 0; j < 32; ++j) mx = fmaxf(mx, ps[tid][j]);
        float sum = 0.f;
        for (int j = 0; j < 32; ++j) { float e = __expf(ps[tid][j] - mx); ps[tid][j] = e; sum += e; }
        float inv = 1.f / sum;
        for (int j = 0; j < 32; ++j) ps[tid][j] *= inv;
    }
    __syncthreads();
    unsigned short* ob = isT ? outT : outR;
    for (int i = tid; i < 2048; i += 256) {
        int s = i >> 6, d = i & 63;
        float acc = 0.f;
#pragma unroll 8
        for (int k = 0; k < 32; ++k) acc += ps[s][k] * vs[k][d];
        ob[((size_t)(b * 32 + s)) * 512 + h * 64 + d] = f2bf(acc);
    }
}

// ---------------- complex self-attention: LDS-resident, grid (128 batch, 2 half) ----------
// R10: 512 threads (8 waves -> 2/SIMD). QK: 1 (row,col) pair per thread.
// PV: er = tid&255, t-range split across tid>>8.
__global__ __launch_bounds__(512) void cattn2_kernel(const float* __restrict__ LL,
                                                     unsigned short* __restrict__ outHi,
                                                     unsigned short* __restrict__ outLo)
{
    extern __shared__ float Xs[];
    __shared__ float Pr[16][33], Pi[16][33];
    const int b = blockIdx.x, half = blockIdx.y;
    const int tid = threadIdx.x;
    const float* base = LL + (size_t)b * 16384;
    for (int i = tid; i < 16384; i += 512) {
        int c = i >> 9, e = i & 511;
        Xs[e * 32 + ((c ^ e) & 31)] = base[i];
    }
    __syncthreads();
    {
        const int li = tid >> 5;                 // 0..15
        const int ci = half * 16 + li;
        const int ck = tid & 31;
        float ar = 0.f, ai = 0.f;
#pragma unroll 4
        for (int er = 0; er < 256; ++er) {
            const int sw = er & 31;
            float yr = Xs[er * 32 + ((ck ^ sw) & 31)];
            float yi = Xs[(er + 256) * 32 + ((ck ^ sw) & 31)];
            float xr = Xs[er * 32 + ((ci ^ sw) & 31)];
            float xi = Xs[(er + 256) * 32 + ((ci ^ sw) & 31)];
            ar += xr * yr - xi * yi;
            ai += xr * yi + xi * yr;
        }
        Pr[li][ck] = ar * 0.0625f;
        Pi[li][ck] = ai * 0.0625f;
    }
    __syncthreads();
    if (tid < 32) {
        int r = tid & 15;
        float (*P)[33] = (tid < 16) ? Pr : Pi;
        float mx = -1e30f;
        for (int j = 0; j < 32; ++j) mx = fmaxf(mx, P[r][j]);
        float s = 0.f;
        for (int j = 0; j < 32; ++j) { float e = __expf(P[r][j] - mx); P[r][j] = e; s += e; }
        float inv = 1.f / s;
        for (int j = 0; j < 32; ++j) P[r][j] *= inv;
    }
    __syncthreads();
    const int er = tid & 255;
    const int th = tid >> 8;                     // 0 or 1: t in [th*8, th*8+8)
    const int sw = er & 31;
    float accr[8], acci[8];
#pragma unroll
    for (int t = 0; t < 8; ++t) { accr[t] = 0.f; acci[t] = 0.f; }
    for (int k = 0; k < 32; ++k) {
        float yr = Xs[er * 32 + ((k ^ sw) & 31)];
        float yi = Xs[(er + 256) * 32 + ((k ^ sw) & 31)];
#pragma unroll
        for (int t = 0; t < 8; ++t) {
            float pr = Pr[th * 8 + t][k], pi = Pi[th * 8 + t][k];
            accr[t] += pr * yr - pi * yi;
            acci[t] += pr * yi + pi * yr;
        }
    }
#pragma unroll
    for (int t = 0; t < 8; ++t) {
        int c = half * 16 + th * 8 + t;
        float vr = Xs[er * 32 + ((c ^ sw) & 31)] + accr[t];
        float vi = Xs[(er + 256) * 32 + ((c ^ sw) & 31)] + acci[t];
        size_t ir = (size_t)b * 16384 + (size_t)c * 512 + er;
        unsigned short hr = f2bf(vr), hi2 = f2bf(vi);
        outHi[ir] = hr;        outLo[ir] = f2bf(vr - bf2f(hr));
        outHi[ir + 256] = hi2; outLo[ir + 256] = f2bf(vi - bf2f(hi2));
    }
}

// ---------------- DUAL add+LN (512), f32 resid, out bf16 hi/lo; rows>=4096 = branch 1 ----
__global__ __launch_bounds__(256) void add_ln_d1(
    const float* __restrict__ r0, const float* __restrict__ y0,
    const float* __restrict__ w0, const float* __restrict__ b0,
    unsigned short* __restrict__ h0, unsigned short* __restrict__ l0,
    const float* __restrict__ r1, const float* __restrict__ y1,
    const float* __restrict__ w1, const float* __restrict__ b1,
    unsigned short* __restrict__ h1, unsigned short* __restrict__ l1)
{
    const int row = blockIdx.x;
    const int br = row >> 12;
    const int rl = row & 4095;
    const float* resid = br ? r1 : r0;
    const float* y     = br ? y1 : y0;
    const float* w     = br ? w1 : w0;
    const float* bb    = br ? b1 : b0;
    unsigned short* oh = br ? h1 : h0;
    unsigned short* ol = br ? l1 : l0;
    const int tid = threadIdx.x;
    const size_t base = (size_t)rl * 512;
    float v0 = resid[base + tid] + y[base + tid];
    float v1 = resid[base + 256 + tid] + y[base + 256 + tid];
    float s = v0 + v1, q = v0 * v0 + v1 * v1;
    for (int off = 32; off; off >>= 1) { s += __shfl_down(s, off); q += __shfl_down(q, off); }
    __shared__ float sw[4], qw[4], ms, is;
    int wid = tid >> 6, lane = tid & 63;
    if (lane == 0) { sw[wid] = s; qw[wid] = q; }
    __syncthreads();
    if (tid == 0) {
        float S = sw[0] + sw[1] + sw[2] + sw[3];
        float Q = qw[0] + qw[1] + qw[2] + qw[3];
        float m = S * (1.f / 512.f);
        ms = m;
        is = rsqrtf(Q * (1.f / 512.f) - m * m + 1e-5f);
    }
    __syncthreads();
    float m = ms, inv = is;
    float o0 = (v0 - m) * inv * w[tid] + bb[tid];
    float o1 = (v1 - m) * inv * w[256 + tid] + bb[256 + tid];
    unsigned short e0 = f2bf(o0), e1 = f2bf(o1);
    oh[base + tid] = e0;       ol[base + tid] = f2bf(o0 - bf2f(e0));
    oh[base + 256 + tid] = e1; ol[base + 256 + tid] = f2bf(o1 - bf2f(e1));
}

// ---------------- DUAL add+LN (512), bf16 hi/lo resid, out f32 --------------------------
__global__ __launch_bounds__(256) void add_ln_d2(
    const unsigned short* __restrict__ rh0, const unsigned short* __restrict__ rl0,
    const float* __restrict__ y0, const float* __restrict__ w0, const float* __restrict__ b0,
    float* __restrict__ o0p,
    const unsigned short* __restrict__ rh1, const unsigned short* __restrict__ rl1,
    const float* __restrict__ y1, const float* __restrict__ w1, const float* __restrict__ b1,
    float* __restrict__ o1p)
{
    const int row = blockIdx.x;
    const int br = row >> 12;
    const int rl = row & 4095;
    const unsigned short* rh = br ? rh1 : rh0;
    const unsigned short* rlo = br ? rl1 : rl0;
    const float* y  = br ? y1 : y0;
    const float* w  = br ? w1 : w0;
    const float* bb = br ? b1 : b0;
    float* op = br ? o1p : o0p;
    const int tid = threadIdx.x;
    const size_t base = (size_t)rl * 512;
    float v0 = bf2f(rh[base + tid]) + bf2f(rlo[base + tid]) + y[base + tid];
    float v1 = bf2f(rh[base + 256 + tid]) + bf2f(rlo[base + 256 + tid]) + y[base + 256 + tid];
    float s = v0 + v1, q = v0 * v0 + v1 * v1;
    for (int off = 32; off; off >>= 1) { s += __shfl_down(s, off); q += __shfl_down(q, off); }
    __shared__ float sw[4], qw[4], ms, is;
    int wid = tid >> 6, lane = tid & 63;
    if (lane == 0) { sw[wid] = s; qw[wid] = q; }
    __syncthreads();
    if (tid == 0) {
        float S = sw[0] + sw[1] + sw[2] + sw[3];
        float Q = qw[0] + qw[1] + qw[2] + qw[3];
        float m = S * (1.f / 512.f);
        ms = m;
        is = rsqrtf(Q * (1.f / 512.f) - m * m + 1e-5f);
    }
    __syncthreads();
    float m = ms, inv = is;
    op[base + tid]       = (v0 - m) * inv * w[tid] + bb[tid];
    op[base + 256 + tid] = (v1 - m) * inv * w[256 + tid] + bb[256 + tid];
}

// ---------------- relu + LayerNorm over (C,S)=16384 per batch, optional final add -------
template <int ADDF>
__global__ __launch_bounds__(256) void relu_bln_kernel(const float* __restrict__ xin,
                                                       const float* __restrict__ w, const float* __restrict__ b,
                                                       const float* __restrict__ addsrc,
                                                       float* __restrict__ out)
{
    const int bb = blockIdx.x;
    const int tid = threadIdx.x;
    const float* xp = xin + (size_t)bb * 16384;
    float s = 0.f, q = 0.f;
    for (int i = tid; i < 16384; i += 256) { float v = fmaxf(xp[i], 0.f); s += v; q += v * v; }
    for (int off = 32; off; off >>= 1) { s += __shfl_down(s, off); q += __shfl_down(q, off); }
    __shared__ float sw[4], qw[4], ms, is;
    int wid = tid >> 6, lane = tid & 63;
    if (lane == 0) { sw[wid] = s; qw[wid] = q; }
    __syncthreads();
    if (tid == 0) {
        float S = sw[0] + sw[1] + sw[2] + sw[3];
        float Q = qw[0] + qw[1] + qw[2] + qw[3];
        float m = S * (1.f / 16384.f);
        ms = m;
        is = rsqrtf(Q * (1.f / 16384.f) - m * m + 1e-5f);
    }
    __syncthreads();
    float m = ms, inv = is;
    const float* ap = ADDF ? (addsrc + (size_t)bb * 16384) : nullptr;
    float* op = out + (size_t)bb * 16384;
    for (int i = tid; i < 16384; i += 256) {
        float v = fmaxf(xp[i], 0.f);
        float o = (v - m) * inv * w[i] + b[i];
        if (ADDF) o += ap[i];
        op[i] = o;
    }
}

extern "C" void kernel_launch(void* const* d_in, const int* in_sizes, int n_in,
                              void* d_out, int out_size, void* d_ws, size_t ws_size,
                              hipStream_t stream)
{
    (void)in_sizes; (void)n_in; (void)out_size; (void)ws_size;
    const float* x        = (const float*)d_in[0];
    const float* t_in_w   = (const float*)d_in[1];
    const float* t_in_b   = (const float*)d_in[2];
    const float* t_out_w  = (const float*)d_in[3];
    const float* t_out_b  = (const float*)d_in[4];
    const float* t_ln1_w  = (const float*)d_in[5];
    const float* t_ln1_b  = (const float*)d_in[6];
    const float* t_lin1_w = (const float*)d_in[7];
    const float* t_lin1_b = (const float*)d_in[8];
    const float* t_lin2_w = (const float*)d_in[9];
    const float* t_lin2_b = (const float*)d_in[10];
    const float* t_ln2_w  = (const float*)d_in[11];
    const float* t_ln2_b  = (const float*)d_in[12];
    const float* r_in_w   = (const float*)d_in[13];
    const float* r_in_b   = (const float*)d_in[14];
    const float* r_out_w  = (const float*)d_in[15];
    const float* r_out_b  = (const float*)d_in[16];
    const float* r_ln1_w  = (const float*)d_in[17];
    const float* r_ln1_b  = (const float*)d_in[18];
    const float* r_lin1_w = (const float*)d_in[19];
    const float* r_lin1_b = (const float*)d_in[20];
    const float* r_lin2_w = (const float*)d_in[21];
    const float* r_lin2_b = (const float*)d_in[22];
    const float* r_ln2_w  = (const float*)d_in[23];
    const float* r_ln2_b  = (const float*)d_in[24];
    const float* lc_w     = (const float*)d_in[25];
    const float* lc_b     = (const float*)d_in[26];
    const float* up1_w    = (const float*)d_in[27];
    const float* up1_b    = (const float*)d_in[28];
    const float* up2_w    = (const float*)d_in[29];
    const float* up2_b    = (const float*)d_in[30];
    const float* n1_w     = (const float*)d_in[31];
    const float* n1_b     = (const float*)d_in[32];
    const float* n2_w     = (const float*)d_in[33];
    const float* n2_b     = (const float*)d_in[34];
    const float* l1_re    = (const float*)d_in[35];
    const float* l1_im    = (const float*)d_in[36];
    const float* lb1_re   = (const float*)d_in[39];
    const float* lb1_im   = (const float*)d_in[40];

    float* outp = (float*)d_out;

    // ---- workspace map (float offsets; total 21,774,336 f = 87.1 MB) ----
    float* WS   = (float*)d_ws;
    float* LL   = WS;                                        // 2M f (also fa f32, later y_r)
    float* FA   = WS;
    float* yR   = WS;
    float* QR   = WS + 2097152;                              // 6.29M f
    float* tabC = QR;                                        // 131072
    float* tabS = QR + 131072;
    unsigned short* WaHu = (unsigned short*)(QR + 786432);
    unsigned short* WaLu = (unsigned short*)(QR + 917504);
    unsigned short* WmHu = (unsigned short*)(QR + 1048576);
    unsigned short* WmLu = (unsigned short*)(QR + 1179648);
    float* qkvR = QR;                                        // 6.29M f (r-qkv f32)
    unsigned short* x1rH = (unsigned short*)(WS + 2097152);
    unsigned short* x1rL = (unsigned short*)(WS + 3145728);
    unsigned short* x1tH = (unsigned short*)(WS + 4194304);
    unsigned short* x1tL = (unsigned short*)(WS + 5242880);
    float* yT   = WS + 6291456;                              // 2M f
    unsigned short* qkvT = (unsigned short*)(WS + 8388608);  // 6.29M ushort
    unsigned short* f1R  = (unsigned short*)(WS + 8388608);  // 8.39M ushort
    float* x2R  = WS + 8388608;                              // 2M f
    float* x2T  = WS + 10485760;                             // 2M f
    unsigned short* xHi = (unsigned short*)(WS + 11534336);
    unsigned short* xLo = (unsigned short*)(WS + 12582912);
    unsigned short* aoR = (unsigned short*)(WS + 11534336);
    unsigned short* aoT = (unsigned short*)(WS + 12582912);
    unsigned short* f1T = (unsigned short*)(WS + 12582912);  // 8.39M ushort
    unsigned short* LLH = (unsigned short*)(WS + 13631488);
    unsigned short* LLL = (unsigned short*)(WS + 14680064);
    unsigned short* u1b = (unsigned short*)(WS + 13631488);
    float* oR   = WS + 13631488;                             // 2M f
    float* oT   = WS + 15728640;                             // 2M f
    unsigned short* faHi = (unsigned short*)(WS + 15728640);
    unsigned short* faLo = (unsigned short*)(WS + 16777216);
    unsigned short* rinLoU = (unsigned short*)(WS + 17825792);  // 786432 ushort
    float* LB   = WS + 18219008;                             // 512 f
    unsigned short* WB = (unsigned short*)(WS + 18366464);

    unsigned short* w_tin  = WB + 0;        // 1536x512
    unsigned short* w_tout = WB + 786432;   // 512x512
    unsigned short* w_tl1  = WB + 1048576;  // 2048x512
    unsigned short* w_tl2  = WB + 2097152;  // 512x2048
    unsigned short* w_rin  = WB + 3145728;  // 1536x512
    unsigned short* w_rout = WB + 3932160;  // 512x512
    unsigned short* w_rl1  = WB + 4194304;  // 2048x512
    unsigned short* w_rl2  = WB + 5242880;  // 512x2048
    unsigned short* w_up1  = WB + 6291456;  // 512x512
    unsigned short* w_up2  = WB + 6553600;  // 512x512

    dim3 blk(256);

    // ---- prep ----
    tab_kernel<<<dim3(512), blk, 0, stream>>>(tabC, tabS);
    wa_kernel<<<dim3(512, 2), blk, 0, stream>>>(l1_re, l1_im, tabC, tabS, WaHu, WaLu);
    wm_kernel<<<dim3(512, 2), blk, 0, stream>>>(lc_w, tabC, tabS, WmHu, WmLu);
    lbpack_kernel<<<dim3(2), blk, 0, stream>>>(lb1_re, lb1_im, LB);
    wcvt_kernel<<<dim3(26624), blk, 0, stream>>>(t_in_w, t_out_w, t_lin1_w, t_lin2_w,
                                                 r_in_w, r_out_w, r_lin1_w, r_lin2_w,
                                                 up1_w, up2_w, WB);
    xsplit_kernel<<<dim3(2048), blk, 0, stream>>>(x, xHi, xLo, outp + NOUT, NOUT);  // x hi/lo + down_x

    // ---- freq branch ----
    gemm_mfma3<64,64,1,0,0><<<dim3(8, 64), blk, 0, stream>>>(xHi, xLo, WaHu, WaLu, LB,
                                                             LL, nullptr, nullptr, nullptr, 512, 512);
    cattn2_kernel<<<dim3(128, 2), dim3(512), 65536, stream>>>(LL, LLH, LLL);         // LL hi/lo
    gemm_mfma3<64,64,0,1,1><<<dim3(8, 64), blk, 0, stream>>>(LLH, LLL, WmHu, WmLu, lc_b,
                                                             FA, outp + 2 * NOUT, faHi, faLo, 512, 512);
    cvt_lo_kernel<<<dim3(768), blk, 0, stream>>>(r_in_w, w_rin, rinLoU, 786432);     // rin lo

    // ---- upsample (fa_hi) ----
    gemm_mfma<64,64,0,0,1><<<dim3(8, 64), blk, 0, stream>>>(faHi, w_up1, up1_b, nullptr, u1b, 512, 512);
    gemm_mfma<64,64,0,1,0><<<dim3(8, 64), blk, 0, stream>>>(u1b, w_up2, up2_b, outp + 3 * NOUT, nullptr, 512, 512);

    // ---- qkv for both TELs ----
    gemm_mfma3<64,128,0,0,0><<<dim3(12, 64), blk, 0, stream>>>(faHi, faLo, w_rin, rinLoU, r_in_b,
                                                               qkvR, nullptr, nullptr, nullptr, 1536, 512);
    gemm_mfma<64,128,0,0,1><<<dim3(12, 64), blk, 0, stream>>>(xHi, w_tin, t_in_b, nullptr, qkvT, 1536, 512);

    // ---- dual TEL pipeline (z / row selects branch: 0=r, 1=t) ----
    attn_dual_kernel<<<dim3(2048), blk, 0, stream>>>(qkvR, qkvT, aoR, aoT);
    gemm_dual<128,64,0,0><<<dim3(8, 32, 2), blk, 0, stream>>>(aoR, aoT, w_rout, w_tout,
                                                              r_out_b, t_out_b, oR, oT,
                                                              nullptr, nullptr, 512, 512);
    add_ln_d1<<<dim3(8192), blk, 0, stream>>>(FA, oR, r_ln1_w, r_ln1_b, x1rH, x1rL,
                                              x,  oT, t_ln1_w, t_ln1_b, x1tH, x1tL);
    gemm_dual<128,128,1,1><<<dim3(16, 32, 2), blk, 0, stream>>>(x1rH, x1tH, w_rl1, w_tl1,
                                                                r_lin1_b, t_lin1_b, nullptr, nullptr,
                                                                f1R, f1T, 2048, 512);
    gemm_dual<128,64,0,0><<<dim3(8, 32, 2), blk, 0, stream>>>(f1R, f1T, w_rl2, w_tl2,
                                                              r_lin2_b, t_lin2_b, yR, yT,
                                                              nullptr, nullptr, 512, 2048);
    add_ln_d2<<<dim3(8192), blk, 0, stream>>>(x1rH, x1rL, yR, r_ln2_w, r_ln2_b, x2R,
                                              x1tH, x1tL, yT, t_ln2_w, t_ln2_b, x2T);
    relu_bln_kernel<0><<<dim3(128), blk, 0, stream>>>(x2R, n2_w, n2_b, nullptr, x2R);      // rf (in-place)
    relu_bln_kernel<1><<<dim3(128), blk, 0, stream>>>(x2T, n1_w, n1_b, x2R, outp);         // res = df + rf
}

// Round 8
// 470.162 us; speedup vs baseline: 1.1143x; 1.1143x over previous
//
#include <hip/hip_runtime.h>
#include <math.h>

// NoiScaleModule: B=128, C=32(seq), S=512(d_model), EMB=256, NHEAD=8, DFF=2048
// All tensors FLOAT32. Outputs concat flat: res[2M], down_x[2M], fa[2M], up[2M]
//
// R11: XCD-chunked blockIdx swizzle on all GEMMs (T1). 557->520.
// R12: all-128 tiles — REGRESSION (grids -> 1 block/CU). R13: BK=64 — NEUTRAL.
// R14: selective 128-tiles — NEUTRAL-neg. GEMM structure is PLATEAUED at ~520.
// R15: attack the schedule, not the kernels: 22 -> 16 dispatches.
//      wa+wm merged; wcvt+rinLo+xsplit+lbpack -> one uber elementwise kernel;
//      qkvR(mfma3)+qkvT(single) -> one dual dispatch; relu_bln x2 -> fused
//      (rf lives in 64KB LDS, never hits HBM). GEMM tiles = R13 best (64-class).

#define NROW 4096
#define NOUT 2097152

typedef __attribute__((ext_vector_type(8))) short short8;
typedef __attribute__((ext_vector_type(4))) float floatx4;

__device__ __forceinline__ unsigned short f2bf(float f) {
    union { float f; unsigned u; } v; v.f = f;
    return (unsigned short)((v.u + 0x7fffu + ((v.u >> 16) & 1u)) >> 16);
}
__device__ __forceinline__ float bf2f(unsigned short h) {
    union { unsigned u; float f; } v; v.u = ((unsigned)h) << 16;
    return v.f;
}

__device__ __forceinline__ void gload16(const unsigned short* g, unsigned short* l) {
    __builtin_amdgcn_global_load_lds((const __attribute__((address_space(1))) void*)g,
                                     (__attribute__((address_space(3))) void*)l, 16, 0, 0);
}

// XCD-chunked swizzle (T1): consecutive dispatch ids round-robin XCDs; remap so
// each XCD gets a contiguous chunk of logical tiles (requires nwg % 8 == 0).
__device__ __forceinline__ void xcd_swizzle(int& bx, int& by, int& bz) {
    const int gx = gridDim.x, gy = gridDim.y;
    const int nwg = gx * gy * gridDim.z;
    int b = (bz * gy + by) * gx + bx;
    const int chunk = nwg >> 3;
    const int lb = (b & 7) * chunk + (b >> 3);
    bx = lb % gx;
    const int rem = lb / gx;
    by = rem % gy;
    bz = rem / gy;
}

// ---------------- prep: cos/sin tables tab[n][k], n<512, k<256 ----------------
__global__ __launch_bounds__(256) void tab_kernel(float* __restrict__ tabC, float* __restrict__ tabS)
{
    int n = blockIdx.x, k = threadIdx.x;
    int m = (n * k) & 511;
    float th = (float)m * 0.01227184630308513f;  // 2*pi/512
    float s, c; sincosf(th, &s, &c);
    tabC[n * 256 + k] = c;
    tabS[n * 256 + k] = s;
}

// Wa (z=0) and Wm (z=1) in one dispatch; both emit bf16 hi/lo directly.
__global__ __launch_bounds__(256) void wawm_kernel(const float* __restrict__ l1_re, const float* __restrict__ l1_im,
                                                   const float* __restrict__ lc_w,
                                                   const float* __restrict__ tabC, const float* __restrict__ tabS,
                                                   unsigned short* __restrict__ WaH, unsigned short* __restrict__ WaL,
                                                   unsigned short* __restrict__ WmH, unsigned short* __restrict__ WmL)
{
    __shared__ float lw[512];
    const float inv = 0.04419417382415922f;  // 1/sqrt(512)
    if (blockIdx.z == 0) {
        int n  = blockIdx.x;
        int ep = blockIdx.y * 256 + threadIdx.x;
        float acc = 0.f;
        if (ep < 256) {
            for (int k = 0; k < 128; ++k) {
                float c = tabC[n * 256 + k], s = tabS[n * 256 + k];
                acc += c * l1_re[k * 256 + ep] + s * l1_im[k * 256 + ep];
            }
        } else {
            int e = ep - 256;
            for (int k = 0; k < 128; ++k) {
                float c = tabC[n * 256 + k], s = tabS[n * 256 + k];
                acc += c * l1_im[k * 256 + e] - s * l1_re[k * 256 + e];
            }
        }
        float v = acc * inv;
        size_t idx = (size_t)ep * 512 + n;
        unsigned short h = f2bf(v);
        WaH[idx] = h;
        WaL[idx] = f2bf(v - bf2f(h));
    } else {
        int s  = blockIdx.x;
        int kk = blockIdx.y * 256 + threadIdx.x;
        for (int i = threadIdx.x; i < 512; i += 256) lw[i] = lc_w[s * 512 + i];
        __syncthreads();
        float acc = 0.f;
        if (kk < 256) {
            int k = kk;
            for (int n = 0; n < 512; ++n) acc += tabC[n * 256 + k] * lw[n];
            acc *= (k == 0) ? inv : 2.f * inv;
        } else {
            int k = kk - 256;
            if (k == 0) acc = 0.f;
            else {
                for (int n = 0; n < 512; ++n) acc += tabS[n * 256 + k] * lw[n];
                acc *= -2.f * inv;
            }
        }
        size_t idx = (size_t)s * 512 + kk;
        unsigned short h = f2bf(acc);
        WmH[idx] = h;
        WmL[idx] = f2bf(acc - bf2f(h));
    }
}

// ---------------- uber elementwise prep: wcvt(+rinLo) | xsplit | lbpack ----------------
// blocks [0,26624): weight cvt (6815744 elems; r_in range also emits lo)
// blocks [26624,34816): xsplit over x (2097152 elems)
// blocks [34816,34818): lbpack (512 elems)
__global__ __launch_bounds__(256) void uber_prep_kernel(
    const float* s0, const float* s1, const float* s2, const float* s3, const float* s4,
    const float* s5, const float* s6, const float* s7, const float* s8, const float* s9,
    unsigned short* __restrict__ o, unsigned short* __restrict__ rinLo,
    const float* __restrict__ x, unsigned short* __restrict__ xhi,
    unsigned short* __restrict__ xlo, float* __restrict__ xcp,
    const float* __restrict__ lbre, const float* __restrict__ lbim, float* __restrict__ lbout)
{
    const int bid = blockIdx.x, tid = threadIdx.x;
    if (bid < 26624) {
        int i = bid * 256 + tid;  // exactly covers 6815744
        const float* s; int off;
        if (i < 3145728) {
            if (i < 1048576) { if (i < 786432) { s = s0; off = 0; } else { s = s1; off = 786432; } }
            else             { if (i < 2097152) { s = s2; off = 1048576; } else { s = s3; off = 2097152; } }
        } else {
            if (i < 5242880) {
                if (i < 3932160) { s = s4; off = 3145728; }
                else if (i < 4194304) { s = s5; off = 3932160; }
                else { s = s6; off = 4194304; }
            } else {
                if (i < 6291456) { s = s7; off = 5242880; }
                else if (i < 6553600) { s = s8; off = 6291456; }
                else { s = s9; off = 6553600; }
            }
        }
        float v = s[i - off];
        unsigned short h = f2bf(v);
        o[i] = h;
        if (i >= 3145728 && i < 3932160) rinLo[i - 3145728] = f2bf(v - bf2f(h));
    } else if (bid < 34816) {
        int i = (bid - 26624) * 256 + tid;  // exactly covers 2097152
        float v = x[i];
        unsigned short h = f2bf(v);
        xhi[i] = h;
        xlo[i] = f2bf(v - bf2f(h));
        xcp[i] = v;
    } else {
        int i = (bid - 34816) * 256 + tid;
        if (i < 512) lbout[i] = (i < 256) ? lbre[i] : lbim[i - 256];
    }
}

// ---------------- MFMA GEMM: C[M,N] = A[M,K](bf16) @ W[N,K](bf16)^T + bias ----------------
// TM x TN tile, BK=64 (2x32 sub-chunks, one sync pair per 64-K), 4 waves (2x2),
// single LDS buffer, XCD-swizzled tiles.
template <int TM, int TN, int ACT, int WF, int WBF>
__global__ __launch_bounds__(256) void gemm_mfma(
    const unsigned short* __restrict__ A, const unsigned short* __restrict__ W,
    const float* __restrict__ bias, float* __restrict__ Cf,
    unsigned short* __restrict__ Cb, int N, int K)
{
    constexpr int MI = TM / 32, NJ = TN / 32;
    constexpr int ARW = TM / 4, BRW = TN / 4;
    __shared__ unsigned short As[2][TM * 32];
    __shared__ unsigned short Bs[2][TN * 32];
    const int tid = threadIdx.x;
    const int wave = tid >> 6, lane = tid & 63;
    int bx = blockIdx.x, by = blockIdx.y, bz = blockIdx.z;
    xcd_swizzle(bx, by, bz);
    const int m0 = by * TM, n0 = bx * TN;
    const int sr = lane >> 2, sc = (lane & 3) * 8;
    const unsigned short* aS = A + (size_t)(m0 + wave * ARW + sr) * K + sc;
    const unsigned short* wS = W + (size_t)(n0 + wave * BRW + sr) * K + sc;
    const int wm = (wave >> 1) * (TM / 2), wn = (wave & 1) * (TN / 2);
    const int fr = lane & 15, fko = (lane >> 4) * 8;

    floatx4 acc[MI][NJ];
#pragma unroll
    for (int i = 0; i < MI; ++i)
#pragma unroll
        for (int j = 0; j < NJ; ++j) acc[i][j] = (floatx4){0.f, 0.f, 0.f, 0.f};

    for (int k0 = 0; k0 < K; k0 += 64) {
#pragma unroll
        for (int h = 0; h < 2; ++h) {
#pragma unroll
            for (int c = 0; c < ARW / 16; ++c)
                gload16(aS + (size_t)(16 * c) * K + k0 + 32 * h, &As[h][(wave * ARW + 16 * c) * 32]);
#pragma unroll
            for (int c = 0; c < BRW / 16; ++c)
                gload16(wS + (size_t)(16 * c) * K + k0 + 32 * h, &Bs[h][(wave * BRW + 16 * c) * 32]);
        }
        __syncthreads();
#pragma unroll
        for (int h = 0; h < 2; ++h) {
            short8 af[MI], bfr[NJ];
#pragma unroll
            for (int i = 0; i < MI; ++i) af[i] = *(const short8*)&As[h][(wm + i * 16 + fr) * 32 + fko];
#pragma unroll
            for (int j = 0; j < NJ; ++j) bfr[j] = *(const short8*)&Bs[h][(wn + j * 16 + fr) * 32 + fko];
#pragma unroll
            for (int i = 0; i < MI; ++i)
#pragma unroll
                for (int j = 0; j < NJ; ++j)
                    acc[i][j] = __builtin_amdgcn_mfma_f32_16x16x32_bf16(af[i], bfr[j], acc[i][j], 0, 0, 0);
        }
        __syncthreads();
    }
    const int r0 = m0 + wm + (lane >> 4) * 4;
#pragma unroll
    for (int i = 0; i < MI; ++i) {
#pragma unroll
        for (int j = 0; j < NJ; ++j) {
            int n = n0 + wn + j * 16 + fr;
            float bv = bias[n];
#pragma unroll
            for (int r = 0; r < 4; ++r) {
                int m = r0 + i * 16 + r;
                size_t idx = (size_t)m * N + n;
                float v = acc[i][j][r] + bv;
                if (ACT) v = fmaxf(v, 0.f);
                if (WF) Cf[idx] = v;
                if (WBF) Cb[idx] = f2bf(v);
            }
        }
    }
}

// ---------------- dual-branch GEMM: z=0 -> (A0,W0,b0)->out0, z=1 -> (A1,W1,b1)->out1 ------
template <int TM, int TN, int ACT, int WBF>
__global__ __launch_bounds__(256) void gemm_dual(
    const unsigned short* __restrict__ A0, const unsigned short* __restrict__ A1,
    const unsigned short* __restrict__ W0, const unsigned short* __restrict__ W1,
    const float* __restrict__ b0, const float* __restrict__ b1,
    float* __restrict__ C0, float* __restrict__ C1,
    unsigned short* __restrict__ D0, unsigned short* __restrict__ D1, int N, int K)
{
    constexpr int MI = TM / 32, NJ = TN / 32;
    constexpr int ARW = TM / 4, BRW = TN / 4;
    __shared__ unsigned short As[2][TM * 32];
    __shared__ unsigned short Bs[2][TN * 32];
    const int tid = threadIdx.x;
    const int wave = tid >> 6, lane = tid & 63;
    int bx = blockIdx.x, by = blockIdx.y, bz = blockIdx.z;
    xcd_swizzle(bx, by, bz);
    const int m0 = by * TM, n0 = bx * TN;
    const int z = bz;
    const unsigned short* A = z ? A1 : A0;
    const unsigned short* W = z ? W1 : W0;
    const float* bias = z ? b1 : b0;
    float* Cf = z ? C1 : C0;
    unsigned short* Cb = z ? D1 : D0;
    const int sr = lane >> 2, sc = (lane & 3) * 8;
    const unsigned short* aS = A + (size_t)(m0 + wave * ARW + sr) * K + sc;
    const unsigned short* wS = W + (size_t)(n0 + wave * BRW + sr) * K + sc;
    const int wm = (wave >> 1) * (TM / 2), wn = (wave & 1) * (TN / 2);
    const int fr = lane & 15, fko = (lane >> 4) * 8;

    floatx4 acc[MI][NJ];
#pragma unroll
    for (int i = 0; i < MI; ++i)
#pragma unroll
        for (int j = 0; j < NJ; ++j) acc[i][j] = (floatx4){0.f, 0.f, 0.f, 0.f};

    for (int k0 = 0; k0 < K; k0 += 64) {
#pragma unroll
        for (int h = 0; h < 2; ++h) {
#pragma unroll
            for (int c = 0; c < ARW / 16; ++c)
                gload16(aS + (size_t)(16 * c) * K + k0 + 32 * h, &As[h][(wave * ARW + 16 * c) * 32]);
#pragma unroll
            for (int c = 0; c < BRW / 16; ++c)
                gload16(wS + (size_t)(16 * c) * K + k0 + 32 * h, &Bs[h][(wave * BRW + 16 * c) * 32]);
        }
        __syncthreads();
#pragma unroll
        for (int h = 0; h < 2; ++h) {
            short8 af[MI], bfr[NJ];
#pragma unroll
            for (int i = 0; i < MI; ++i) af[i] = *(const short8*)&As[h][(wm + i * 16 + fr) * 32 + fko];
#pragma unroll
            for (int j = 0; j < NJ; ++j) bfr[j] = *(const short8*)&Bs[h][(wn + j * 16 + fr) * 32 + fko];
#pragma unroll
            for (int i = 0; i < MI; ++i)
#pragma unroll
                for (int j = 0; j < NJ; ++j)
                    acc[i][j] = __builtin_amdgcn_mfma_f32_16x16x32_bf16(af[i], bfr[j], acc[i][j], 0, 0, 0);
        }
        __syncthreads();
    }
    const int r0 = m0 + wm + (lane >> 4) * 4;
#pragma unroll
    for (int i = 0; i < MI; ++i) {
#pragma unroll
        for (int j = 0; j < NJ; ++j) {
            int n = n0 + wn + j * 16 + fr;
            float bv = bias[n];
#pragma unroll
            for (int r = 0; r < 4; ++r) {
                int m = r0 + i * 16 + r;
                size_t idx = (size_t)m * N + n;
                float v = acc[i][j][r] + bv;
                if (ACT) v = fmaxf(v, 0.f);
                if (WBF) Cb[idx] = f2bf(v);
                else     Cf[idx] = v;
            }
        }
    }
}

// ---------------- fused hi/lo 3-product MFMA GEMM (BK=64, single-buffer) ----------------
template <int TM, int TN, int ACT, int WCOPY, int WHILO>
__global__ __launch_bounds__(256) void gemm_mfma3(
    const unsigned short* __restrict__ Ah, const unsigned short* __restrict__ Al,
    const unsigned short* __restrict__ Wh, const unsigned short* __restrict__ Wl,
    const float* __restrict__ bias, float* __restrict__ Cf, float* __restrict__ Ccopy,
    unsigned short* __restrict__ Hh, unsigned short* __restrict__ Hl, int N, int K)
{
    constexpr int MI = TM / 32, NJ = TN / 32;
    constexpr int ARW = TM / 4, BRW = TN / 4;
    __shared__ unsigned short Ash[2][TM * 32];
    __shared__ unsigned short Asl[2][TM * 32];
    __shared__ unsigned short Bsh[2][TN * 32];
    __shared__ unsigned short Bsl[2][TN * 32];
    const int tid = threadIdx.x;
    const int wave = tid >> 6, lane = tid & 63;
    int bx = blockIdx.x, by = blockIdx.y, bz = blockIdx.z;
    xcd_swizzle(bx, by, bz);
    const int m0 = by * TM, n0 = bx * TN;
    const int sr = lane >> 2, sc = (lane & 3) * 8;
    const size_t aoff = (size_t)(m0 + wave * ARW + sr) * K + sc;
    const size_t woff = (size_t)(n0 + wave * BRW + sr) * K + sc;
    const int wm = (wave >> 1) * (TM / 2), wn = (wave & 1) * (TN / 2);
    const int fr = lane & 15, fko = (lane >> 4) * 8;

    floatx4 acc[MI][NJ];
#pragma unroll
    for (int i = 0; i < MI; ++i)
#pragma unroll
        for (int j = 0; j < NJ; ++j) acc[i][j] = (floatx4){0.f, 0.f, 0.f, 0.f};

    for (int k0 = 0; k0 < K; k0 += 64) {
#pragma unroll
        for (int h = 0; h < 2; ++h) {
#pragma unroll
            for (int c = 0; c < ARW / 16; ++c) {
                gload16(Ah + aoff + (size_t)(16 * c) * K + k0 + 32 * h, &Ash[h][(wave * ARW + 16 * c) * 32]);
                gload16(Al + aoff + (size_t)(16 * c) * K + k0 + 32 * h, &Asl[h][(wave * ARW + 16 * c) * 32]);
            }
#pragma unroll
            for (int c = 0; c < BRW / 16; ++c) {
                gload16(Wh + woff + (size_t)(16 * c) * K + k0 + 32 * h, &Bsh[h][(wave * BRW + 16 * c) * 32]);
                gload16(Wl + woff + (size_t)(16 * c) * K + k0 + 32 * h, &Bsl[h][(wave * BRW + 16 * c) * 32]);
            }
        }
        __syncthreads();
#pragma unroll
        for (int h = 0; h < 2; ++h) {
            short8 ah[MI], al[MI], bh[NJ], bl[NJ];
#pragma unroll
            for (int i = 0; i < MI; ++i) {
                ah[i] = *(const short8*)&Ash[h][(wm + i * 16 + fr) * 32 + fko];
                al[i] = *(const short8*)&Asl[h][(wm + i * 16 + fr) * 32 + fko];
            }
#pragma unroll
            for (int j = 0; j < NJ; ++j) {
                bh[j] = *(const short8*)&Bsh[h][(wn + j * 16 + fr) * 32 + fko];
                bl[j] = *(const short8*)&Bsl[h][(wn + j * 16 + fr) * 32 + fko];
            }
#pragma unroll
            for (int i = 0; i < MI; ++i)
#pragma unroll
                for (int j = 0; j < NJ; ++j) {
                    acc[i][j] = __builtin_amdgcn_mfma_f32_16x16x32_bf16(al[i], bh[j], acc[i][j], 0, 0, 0);
                    acc[i][j] = __builtin_amdgcn_mfma_f32_16x16x32_bf16(ah[i], bl[j], acc[i][j], 0, 0, 0);
                    acc[i][j] = __builtin_amdgcn_mfma_f32_16x16x32_bf16(ah[i], bh[j], acc[i][j], 0, 0, 0);
                }
        }
        __syncthreads();
    }
    const int r0 = m0 + wm + (lane >> 4) * 4;
#pragma unroll
    for (int i = 0; i < MI; ++i) {
#pragma unroll
        for (int j = 0; j < NJ; ++j) {
            int n = n0 + wn + j * 16 + fr;
            float bv = bias[n];
#pragma unroll
            for (int r = 0; r < 4; ++r) {
                int m = r0 + i * 16 + r;
                size_t idx = (size_t)m * N + n;
                float v = acc[i][j][r] + bv;
                if (ACT) v = fmaxf(v, 0.f);
                Cf[idx] = v;
                if (WCOPY) Ccopy[idx] = v;
                if (WHILO) {
                    unsigned short h = f2bf(v);
                    Hh[idx] = h;
                    Hl[idx] = f2bf(v - bf2f(h));
                }
            }
        }
    }
}

// ---------------- merged qkv GEMM: z=0 -> r-branch 3-product (f32 out),
//                  z=1 -> t-branch single-product (bf16 out). BK=64. --------------------
template <int TM, int TN>
__global__ __launch_bounds__(256) void gemm_qkv_dual(
    const unsigned short* __restrict__ Ah0, const unsigned short* __restrict__ Al0,
    const unsigned short* __restrict__ Wh0, const unsigned short* __restrict__ Wl0,
    const float* __restrict__ b0, float* __restrict__ C0,
    const unsigned short* __restrict__ A1, const unsigned short* __restrict__ W1,
    const float* __restrict__ b1, unsigned short* __restrict__ C1,
    int N, int K)
{
    constexpr int MI = TM / 32, NJ = TN / 32;
    constexpr int ARW = TM / 4, BRW = TN / 4;
    __shared__ unsigned short Ash[2][TM * 32];
    __shared__ unsigned short Asl[2][TM * 32];
    __shared__ unsigned short Bsh[2][TN * 32];
    __shared__ unsigned short Bsl[2][TN * 32];
    const int tid = threadIdx.x;
    const int wave = tid >> 6, lane = tid & 63;
    int bx = blockIdx.x, by = blockIdx.y, bz = blockIdx.z;
    xcd_swizzle(bx, by, bz);
    const int m0 = by * TM, n0 = bx * TN;
    const int sr = lane >> 2, sc = (lane & 3) * 8;
    const size_t aoff = (size_t)(m0 + wave * ARW + sr) * K + sc;
    const size_t woff = (size_t)(n0 + wave * BRW + sr) * K + sc;
    const int wm = (wave >> 1) * (TM / 2), wn = (wave & 1) * (TN / 2);
    const int fr = lane & 15, fko = (lane >> 4) * 8;

    floatx4 acc[MI][NJ];
#pragma unroll
    for (int i = 0; i < MI; ++i)
#pragma unroll
        for (int j = 0; j < NJ; ++j) acc[i][j] = (floatx4){0.f, 0.f, 0.f, 0.f};

    const int r0 = m0 + wm + (lane >> 4) * 4;

    if (bz == 0) {
        // ---- r-branch: 3-product hi/lo ----
        for (int k0 = 0; k0 < K; k0 += 64) {
#pragma unroll
            for (int h = 0; h < 2; ++h) {
#pragma unroll
                for (int c = 0; c < ARW / 16; ++c) {
                    gload16(Ah0 + aoff + (size_t)(16 * c) * K + k0 + 32 * h, &Ash[h][(wave * ARW + 16 * c) * 32]);
                    gload16(Al0 + aoff + (size_t)(16 * c) * K + k0 + 32 * h, &Asl[h][(wave * ARW + 16 * c) * 32]);
                }
#pragma unroll
                for (int c = 0; c < BRW / 16; ++c) {
                    gload16(Wh0 + woff + (size_t)(16 * c) * K + k0 + 32 * h, &Bsh[h][(wave * BRW + 16 * c) * 32]);
                    gload16(Wl0 + woff + (size_t)(16 * c) * K + k0 + 32 * h, &Bsl[h][(wave * BRW + 16 * c) * 32]);
                }
            }
            __syncthreads();
#pragma unroll
            for (int h = 0; h < 2; ++h) {
                short8 ah[MI], al[MI], bh[NJ], bl[NJ];
#pragma unroll
                for (int i = 0; i < MI; ++i) {
                    ah[i] = *(const short8*)&Ash[h][(wm + i * 16 + fr) * 32 + fko];
                    al[i] = *(const short8*)&Asl[h][(wm + i * 16 + fr) * 32 + fko];
                }
#pragma unroll
                for (int j = 0; j < NJ; ++j) {
                    bh[j] = *(const short8*)&Bsh[h][(wn + j * 16 + fr) * 32 + fko];
                    bl[j] = *(const short8*)&Bsl[h][(wn + j * 16 + fr) * 32 + fko];
                }
#pragma unroll
                for (int i = 0; i < MI; ++i)
#pragma unroll
                    for (int j = 0; j < NJ; ++j) {
                        acc[i][j] = __builtin_amdgcn_mfma_f32_16x16x32_bf16(al[i], bh[j], acc[i][j], 0, 0, 0);
                        acc[i][j] = __builtin_amdgcn_mfma_f32_16x16x32_bf16(ah[i], bl[j], acc[i][j], 0, 0, 0);
                        acc[i][j] = __builtin_amdgcn_mfma_f32_16x16x32_bf16(ah[i], bh[j], acc[i][j], 0, 0, 0);
                    }
            }
            __syncthreads();
        }
#pragma unroll
        for (int i = 0; i < MI; ++i)
#pragma unroll
            for (int j = 0; j < NJ; ++j) {
                int n = n0 + wn + j * 16 + fr;
                float bv = b0[n];
#pragma unroll
                for (int r = 0; r < 4; ++r) {
                    int m = r0 + i * 16 + r;
                    C0[(size_t)m * N + n] = acc[i][j][r] + bv;
                }
            }
    } else {
        // ---- t-branch: single product ----
        for (int k0 = 0; k0 < K; k0 += 64) {
#pragma unroll
            for (int h = 0; h < 2; ++h) {
#pragma unroll
                for (int c = 0; c < ARW / 16; ++c)
                    gload16(A1 + aoff + (size_t)(16 * c) * K + k0 + 32 * h, &Ash[h][(wave * ARW + 16 * c) * 32]);
#pragma unroll
                for (int c = 0; c < BRW / 16; ++c)
                    gload16(W1 + woff + (size_t)(16 * c) * K + k0 + 32 * h, &Bsh[h][(wave * BRW + 16 * c) * 32]);
            }
            __syncthreads();
#pragma unroll
            for (int h = 0; h < 2; ++h) {
                short8 af[MI], bfr[NJ];
#pragma unroll
                for (int i = 0; i < MI; ++i) af[i] = *(const short8*)&Ash[h][(wm + i * 16 + fr) * 32 + fko];
#pragma unroll
                for (int j = 0; j < NJ; ++j) bfr[j] = *(const short8*)&Bsh[h][(wn + j * 16 + fr) * 32 + fko];
#pragma unroll
                for (int i = 0; i < MI; ++i)
#pragma unroll
                    for (int j = 0; j < NJ; ++j)
                        acc[i][j] = __builtin_amdgcn_mfma_f32_16x16x32_bf16(af[i], bfr[j], acc[i][j], 0, 0, 0);
            }
            __syncthreads();
        }
#pragma unroll
        for (int i = 0; i < MI; ++i)
#pragma unroll
            for (int j = 0; j < NJ; ++j) {
                int n = n0 + wn + j * 16 + fr;
                float bv = b1[n];
#pragma unroll
                for (int r = 0; r < 4; ++r) {
                    int m = r0 + i * 16 + r;
                    C1[(size_t)m * N + n] = f2bf(acc[i][j][r] + bv);
                }
            }
    }
}

// ---------------- TEL attention, DUAL: blocks [0,1024) = r (f32 qkv), [1024,2048) = t ----
__global__ __launch_bounds__(256) void attn_dual_kernel(const float* __restrict__ qkvF,
                                                        const unsigned short* __restrict__ qkvB,
                                                        unsigned short* __restrict__ outR,
                                                        unsigned short* __restrict__ outT)
{
    const int isT = blockIdx.x >> 10;
    const int bid = blockIdx.x & 1023;
    const int b = bid >> 3;
    const int h = bid & 7;
    __shared__ float qs[32][65], ks[32][65], vs[32][65];
    __shared__ float ps[32][33];
    const int tid = threadIdx.x;
    if (isT) {
        for (int i = tid; i < 2048; i += 256) {
            int s = i >> 6, d = i & 63;
            size_t base = ((size_t)(b * 32 + s)) * 1536 + h * 64 + d;
            qs[s][d] = bf2f(qkvB[base]);
            ks[s][d] = bf2f(qkvB[base + 512]);
            vs[s][d] = bf2f(qkvB[base + 1024]);
        }
    } else {
        for (int i = tid; i < 2048; i += 256) {
            int s = i >> 6, d = i & 63;
            size_t base = ((size_t)(b * 32 + s)) * 1536 + h * 64 + d;
            qs[s][d] = qkvF[base];
            ks[s][d] = qkvF[base + 512];
            vs[s][d] = qkvF[base + 1024];
        }
    }
    __syncthreads();
    for (int i = tid; i < 1024; i += 256) {
        int si = i >> 5, sj = i & 31;
        float acc = 0.f;
#pragma unroll 8
        for (int d = 0; d < 64; ++d) acc += qs[si][d] * ks[sj][d];
        ps[si][sj] = acc * 0.125f;
    }
    __syncthreads();
    if (tid < 32) {
        float mx = -1e30f;
        for (int j = 0; j < 32; ++j) mx = fmaxf(mx, ps[tid][j]);
        float sum = 0.f;
        for (int j = 0; j < 32; ++j) { float e = __expf(ps[tid][j] - mx); ps[tid][j] = e; sum += e; }
        float inv = 1.f / sum;
        for (int j = 0; j < 32; ++j) ps[tid][j] *= inv;
    }
    __syncthreads();
    unsigned short* ob = isT ? outT : outR;
    for (int i = tid; i < 2048; i += 256) {
        int s = i >> 6, d = i & 63;
        float acc = 0.f;
#pragma unroll 8
        for (int k = 0; k < 32; ++k) acc += ps[s][k] * vs[k][d];
        ob[((size_t)(b * 32 + s)) * 512 + h * 64 + d] = f2bf(acc);
    }
}

// ---------------- complex self-attention: LDS-resident, grid (128 batch, 2 half) ----------
// R10: 512 threads (8 waves -> 2/SIMD). QK: 1 (row,col) pair per thread.
// PV: er = tid&255, t-range split across tid>>8.
__global__ __launch_bounds__(512) void cattn2_kernel(const float* __restrict__ LL,
                                                     unsigned short* __restrict__ outHi,
                                                     unsigned short* __restrict__ outLo)
{
    extern __shared__ float Xs[];
    __shared__ float Pr[16][33], Pi[16][33];
    const int b = blockIdx.x, half = blockIdx.y;
    const int tid = threadIdx.x;
    const float* base = LL + (size_t)b * 16384;
    for (int i = tid; i < 16384; i += 512) {
        int c = i >> 9, e = i & 511;
        Xs[e * 32 + ((c ^ e) & 31)] = base[i];
    }
    __syncthreads();
    {
        const int li = tid >> 5;                 // 0..15
        const int ci = half * 16 + li;
        const int ck = tid & 31;
        float ar = 0.f, ai = 0.f;
#pragma unroll 4
        for (int er = 0; er < 256; ++er) {
            const int sw = er & 31;
            float yr = Xs[er * 32 + ((ck ^ sw) & 31)];
            float yi = Xs[(er + 256) * 32 + ((ck ^ sw) & 31)];
            float xr = Xs[er * 32 + ((ci ^ sw) & 31)];
            float xi = Xs[(er + 256) * 32 + ((ci ^ sw) & 31)];
            ar += xr * yr - xi * yi;
            ai += xr * yi + xi * yr;
        }
        Pr[li][ck] = ar * 0.0625f;
        Pi[li][ck] = ai * 0.0625f;
    }
    __syncthreads();
    if (tid < 32) {
        int r = tid & 15;
        float (*P)[33] = (tid < 16) ? Pr : Pi;
        float mx = -1e30f;
        for (int j = 0; j < 32; ++j) mx = fmaxf(mx, P[r][j]);
        float s = 0.f;
        for (int j = 0; j < 32; ++j) { float e = __expf(P[r][j] - mx); P[r][j] = e; s += e; }
        float inv = 1.f / s;
        for (int j = 0; j < 32; ++j) P[r][j] *= inv;
    }
    __syncthreads();
    const int er = tid & 255;
    const int th = tid >> 8;                     // 0 or 1: t in [th*8, th*8+8)
    const int sw = er & 31;
    float accr[8], acci[8];
#pragma unroll
    for (int t = 0; t < 8; ++t) { accr[t] = 0.f; acci[t] = 0.f; }
    for (int k = 0; k < 32; ++k) {
        float yr = Xs[er * 32 + ((k ^ sw) & 31)];
        float yi = Xs[(er + 256) * 32 + ((k ^ sw) & 31)];
#pragma unroll
        for (int t = 0; t < 8; ++t) {
            float pr = Pr[th * 8 + t][k], pi = Pi[th * 8 + t][k];
            accr[t] += pr * yr - pi * yi;
            acci[t] += pr * yi + pi * yr;
        }
    }
#pragma unroll
    for (int t = 0; t < 8; ++t) {
        int c = half * 16 + th * 8 + t;
        float vr = Xs[er * 32 + ((c ^ sw) & 31)] + accr[t];
        float vi = Xs[(er + 256) * 32 + ((c ^ sw) & 31)] + acci[t];
        size_t ir = (size_t)b * 16384 + (size_t)c * 512 + er;
        unsigned short hr = f2bf(vr), hi2 = f2bf(vi);
        outHi[ir] = hr;        outLo[ir] = f2bf(vr - bf2f(hr));
        outHi[ir + 256] = hi2; outLo[ir + 256] = f2bf(vi - bf2f(hi2));
    }
}

// ---------------- DUAL add+LN (512), f32 resid, out bf16 hi/lo; rows>=4096 = branch 1 ----
__global__ __launch_bounds__(256) void add_ln_d1(
    const float* __restrict__ r0, const float* __restrict__ y0,
    const float* __restrict__ w0, const float* __restrict__ b0,
    unsigned short* __restrict__ h0, unsigned short* __restrict__ l0,
    const float* __restrict__ r1, const float* __restrict__ y1,
    const float* __restrict__ w1, const float* __restrict__ b1,
    unsigned short* __restrict__ h1, unsigned short* __restrict__ l1)
{
    const int row = blockIdx.x;
    const int br = row >> 12;
    const int rl = row & 4095;
    const float* resid = br ? r1 : r0;
    const float* y     = br ? y1 : y0;
    const float* w     = br ? w1 : w0;
    const float* bb    = br ? b1 : b0;
    unsigned short* oh = br ? h1 : h0;
    unsigned short* ol = br ? l1 : l0;
    const int tid = threadIdx.x;
    const size_t base = (size_t)rl * 512;
    float v0 = resid[base + tid] + y[base + tid];
    float v1 = resid[base + 256 + tid] + y[base + 256 + tid];
    float s = v0 + v1, q = v0 * v0 + v1 * v1;
    for (int off = 32; off; off >>= 1) { s += __shfl_down(s, off); q += __shfl_down(q, off); }
    __shared__ float sw[4], qw[4], ms, is;
    int wid = tid >> 6, lane = tid & 63;
    if (lane == 0) { sw[wid] = s; qw[wid] = q; }
    __syncthreads();
    if (tid == 0) {
        float S = sw[0] + sw[1] + sw[2] + sw[3];
        float Q = qw[0] + qw[1] + qw[2] + qw[3];
        float m = S * (1.f / 512.f);
        ms = m;
        is = rsqrtf(Q * (1.f / 512.f) - m * m + 1e-5f);
    }
    __syncthreads();
    float m = ms, inv = is;
    float o0 = (v0 - m) * inv * w[tid] + bb[tid];
    float o1 = (v1 - m) * inv * w[256 + tid] + bb[256 + tid];
    unsigned short e0 = f2bf(o0), e1 = f2bf(o1);
    oh[base + tid] = e0;       ol[base + tid] = f2bf(o0 - bf2f(e0));
    oh[base + 256 + tid] = e1; ol[base + 256 + tid] = f2bf(o1 - bf2f(e1));
}

// ---------------- DUAL add+LN (512), bf16 hi/lo resid, out f32 --------------------------
__global__ __launch_bounds__(256) void add_ln_d2(
    const unsigned short* __restrict__ rh0, const unsigned short* __restrict__ rl0,
    const float* __restrict__ y0, const float* __restrict__ w0, const float* __restrict__ b0,
    float* __restrict__ o0p,
    const unsigned short* __restrict__ rh1, const unsigned short* __restrict__ rl1,
    const float* __restrict__ y1, const float* __restrict__ w1, const float* __restrict__ b1,
    float* __restrict__ o1p)
{
    const int row = blockIdx.x;
    const int br = row >> 12;
    const int rl = row & 4095;
    const unsigned short* rh = br ? rh1 : rh0;
    const unsigned short* rlo = br ? rl1 : rl0;
    const float* y  = br ? y1 : y0;
    const float* w  = br ? w1 : w0;
    const float* bb = br ? b1 : b0;
    float* op = br ? o1p : o0p;
    const int tid = threadIdx.x;
    const size_t base = (size_t)rl * 512;
    float v0 = bf2f(rh[base + tid]) + bf2f(rlo[base + tid]) + y[base + tid];
    float v1 = bf2f(rh[base + 256 + tid]) + bf2f(rlo[base + 256 + tid]) + y[base + 256 + tid];
    float s = v0 + v1, q = v0 * v0 + v1 * v1;
    for (int off = 32; off; off >>= 1) { s += __shfl_down(s, off); q += __shfl_down(q, off); }
    __shared__ float sw[4], qw[4], ms, is;
    int wid = tid >> 6, lane = tid & 63;
    if (lane == 0) { sw[wid] = s; qw[wid] = q; }
    __syncthreads();
    if (tid == 0) {
        float S = sw[0] + sw[1] + sw[2] + sw[3];
        float Q = qw[0] + qw[1] + qw[2] + qw[3];
        float m = S * (1.f / 512.f);
        ms = m;
        is = rsqrtf(Q * (1.f / 512.f) - m * m + 1e-5f);
    }
    __syncthreads();
    float m = ms, inv = is;
    op[base + tid]       = (v0 - m) * inv * w[tid] + bb[tid];
    op[base + 256 + tid] = (v1 - m) * inv * w[256 + tid] + bb[256 + tid];
}

// ---------------- fused relu+batchLN x2: rf = LN(relu(x2R)) kept in LDS,
//                  res = LN(relu(x2T)) + rf. One block per batch, 1024 threads. ----------
__global__ __launch_bounds__(1024) void relu_bln_fused(
    const float* __restrict__ xR, const float* __restrict__ w2, const float* __restrict__ b2,
    const float* __restrict__ xT, const float* __restrict__ w1, const float* __restrict__ b1,
    float* __restrict__ out)
{
    __shared__ float rfs[16384];
    __shared__ float sw_[16], qw_[16], ms_, is_;
    const int bb = blockIdx.x, tid = threadIdx.x;
    const int wid = tid >> 6, lane = tid & 63;
    // pass 1: rf = LN(relu(xR[bb]))
    const float* xr = xR + (size_t)bb * 16384;
    float s = 0.f, q = 0.f;
    for (int i = tid; i < 16384; i += 1024) { float v = fmaxf(xr[i], 0.f); s += v; q += v * v; }
    for (int off = 32; off; off >>= 1) { s += __shfl_down(s, off); q += __shfl_down(q, off); }
    if (lane == 0) { sw_[wid] = s; qw_[wid] = q; }
    __syncthreads();
    if (tid == 0) {
        float S = 0.f, Q = 0.f;
        for (int i = 0; i < 16; ++i) { S += sw_[i]; Q += qw_[i]; }
        float m = S * (1.f / 16384.f);
        ms_ = m;
        is_ = rsqrtf(Q * (1.f / 16384.f) - m * m + 1e-5f);
    }
    __syncthreads();
    float m = ms_, inv = is_;
    for (int i = tid; i < 16384; i += 1024) {
        float v = fmaxf(xr[i], 0.f);
        rfs[i] = (v - m) * inv * w2[i] + b2[i];
    }
    // pass 2: res = LN(relu(xT[bb])) + rf
    const float* xt = xT + (size_t)bb * 16384;
    s = 0.f; q = 0.f;
    for (int i = tid; i < 16384; i += 1024) { float v = fmaxf(xt[i], 0.f); s += v; q += v * v; }
    for (int off = 32; off; off >>= 1) { s += __shfl_down(s, off); q += __shfl_down(q, off); }
    if (lane == 0) { sw_[wid] = s; qw_[wid] = q; }
    __syncthreads();
    if (tid == 0) {
        float S = 0.f, Q = 0.f;
        for (int i = 0; i < 16; ++i) { S += sw_[i]; Q += qw_[i]; }
        float m2 = S * (1.f / 16384.f);
        ms_ = m2;
        is_ = rsqrtf(Q * (1.f / 16384.f) - m2 * m2 + 1e-5f);
    }
    __syncthreads();
    m = ms_; inv = is_;
    float* op = out + (size_t)bb * 16384;
    for (int i = tid; i < 16384; i += 1024) {
        float v = fmaxf(xt[i], 0.f);
        op[i] = (v - m) * inv * w1[i] + b1[i] + rfs[i];
    }
}

extern "C" void kernel_launch(void* const* d_in, const int* in_sizes, int n_in,
                              void* d_out, int out_size, void* d_ws, size_t ws_size,
                              hipStream_t stream)
{
    (void)in_sizes; (void)n_in; (void)out_size; (void)ws_size;
    const float* x        = (const float*)d_in[0];
    const float* t_in_w   = (const float*)d_in[1];
    const float* t_in_b   = (const float*)d_in[2];
    const float* t_out_w  = (const float*)d_in[3];
    const float* t_out_b  = (const float*)d_in[4];
    const float* t_ln1_w  = (const float*)d_in[5];
    const float* t_ln1_b  = (const float*)d_in[6];
    const float* t_lin1_w = (const float*)d_in[7];
    const float* t_lin1_b = (const float*)d_in[8];
    const float* t_lin2_w = (const float*)d_in[9];
    const float* t_lin2_b = (const float*)d_in[10];
    const float* t_ln2_w  = (const float*)d_in[11];
    const float* t_ln2_b  = (const float*)d_in[12];
    const float* r_in_w   = (const float*)d_in[13];
    const float* r_in_b   = (const float*)d_in[14];
    const float* r_out_w  = (const float*)d_in[15];
    const float* r_out_b  = (const float*)d_in[16];
    const float* r_ln1_w  = (const float*)d_in[17];
    const float* r_ln1_b  = (const float*)d_in[18];
    const float* r_lin1_w = (const float*)d_in[19];
    const float* r_lin1_b = (const float*)d_in[20];
    const float* r_lin2_w = (const float*)d_in[21];
    const float* r_lin2_b = (const float*)d_in[22];
    const float* r_ln2_w  = (const float*)d_in[23];
    const float* r_ln2_b  = (const float*)d_in[24];
    const float* lc_w     = (const float*)d_in[25];
    const float* lc_b     = (const float*)d_in[26];
    const float* up1_w    = (const float*)d_in[27];
    const float* up1_b    = (const float*)d_in[28];
    const float* up2_w    = (const float*)d_in[29];
    const float* up2_b    = (const float*)d_in[30];
    const float* n1_w     = (const float*)d_in[31];
    const float* n1_b     = (const float*)d_in[32];
    const float* n2_w     = (const float*)d_in[33];
    const float* n2_b     = (const float*)d_in[34];
    const float* l1_re    = (const float*)d_in[35];
    const float* l1_im    = (const float*)d_in[36];
    const float* lb1_re   = (const float*)d_in[39];
    const float* lb1_im   = (const float*)d_in[40];

    float* outp = (float*)d_out;

    // ---- workspace map (float offsets; total 21,774,336 f = 87.1 MB) ----
    float* WS   = (float*)d_ws;
    float* LL   = WS;                                        // 2M f (also fa f32, later y_r)
    float* FA   = WS;
    float* yR   = WS;
    float* QR   = WS + 2097152;                              // 6.29M f
    float* tabC = QR;                                        // 131072
    float* tabS = QR + 131072;
    unsigned short* WaHu = (unsigned short*)(QR + 786432);
    unsigned short* WaLu = (unsigned short*)(QR + 917504);
    unsigned short* WmHu = (unsigned short*)(QR + 1048576);
    unsigned short* WmLu = (unsigned short*)(QR + 1179648);
    float* qkvR = QR;                                        // 6.29M f (r-qkv f32)
    unsigned short* x1rH = (unsigned short*)(WS + 2097152);
    unsigned short* x1rL = (unsigned short*)(WS + 3145728);
    unsigned short* x1tH = (unsigned short*)(WS + 4194304);
    unsigned short* x1tL = (unsigned short*)(WS + 5242880);
    float* yT   = WS + 6291456;                              // 2M f
    unsigned short* qkvT = (unsigned short*)(WS + 8388608);  // 6.29M ushort
    unsigned short* f1R  = (unsigned short*)(WS + 8388608);  // 8.39M ushort
    float* x2R  = WS + 8388608;                              // 2M f
    float* x2T  = WS + 10485760;                             // 2M f
    unsigned short* xHi = (unsigned short*)(WS + 11534336);
    unsigned short* xLo = (unsigned short*)(WS + 12582912);
    unsigned short* aoR = (unsigned short*)(WS + 11534336);
    unsigned short* aoT = (unsigned short*)(WS + 12582912);
    unsigned short* f1T = (unsigned short*)(WS + 12582912);  // 8.39M ushort
    unsigned short* LLH = (unsigned short*)(WS + 13631488);
    unsigned short* LLL = (unsigned short*)(WS + 14680064);
    unsigned short* u1b = (unsigned short*)(WS + 13631488);
    float* oR   = WS + 13631488;                             // 2M f
    float* oT   = WS + 15728640;                             // 2M f
    unsigned short* faHi = (unsigned short*)(WS + 15728640);
    unsigned short* faLo = (unsigned short*)(WS + 16777216);
    unsigned short* rinLoU = (unsigned short*)(WS + 17825792);  // 786432 ushort
    float* LB   = WS + 18219008;                             // 512 f
    unsigned short* WB = (unsigned short*)(WS + 18366464);

    unsigned short* w_tin  = WB + 0;        // 1536x512
    unsigned short* w_tout = WB + 786432;   // 512x512
    unsigned short* w_tl1  = WB + 1048576;  // 2048x512
    unsigned short* w_tl2  = WB + 2097152;  // 512x2048
    unsigned short* w_rin  = WB + 3145728;  // 1536x512
    unsigned short* w_rout = WB + 3932160;  // 512x512
    unsigned short* w_rl1  = WB + 4194304;  // 2048x512
    unsigned short* w_rl2  = WB + 5242880;  // 512x2048
    unsigned short* w_up1  = WB + 6291456;  // 512x512
    unsigned short* w_up2  = WB + 6553600;  // 512x512

    dim3 blk(256);

    // ---- prep (3 dispatches) ----
    tab_kernel<<<dim3(512), blk, 0, stream>>>(tabC, tabS);
    wawm_kernel<<<dim3(512, 2, 2), blk, 0, stream>>>(l1_re, l1_im, lc_w, tabC, tabS,
                                                     WaHu, WaLu, WmHu, WmLu);
    uber_prep_kernel<<<dim3(34818), blk, 0, stream>>>(t_in_w, t_out_w, t_lin1_w, t_lin2_w,
                                                      r_in_w, r_out_w, r_lin1_w, r_lin2_w,
                                                      up1_w, up2_w, WB, rinLoU,
                                                      x, xHi, xLo, outp + NOUT,
                                                      lb1_re, lb1_im, LB);

    // ---- freq branch ----
    gemm_mfma3<64,64,1,0,0><<<dim3(8, 64), blk, 0, stream>>>(xHi, xLo, WaHu, WaLu, LB,
                                                             LL, nullptr, nullptr, nullptr, 512, 512);
    cattn2_kernel<<<dim3(128, 2), dim3(512), 65536, stream>>>(LL, LLH, LLL);         // LL hi/lo
    gemm_mfma3<64,64,0,1,1><<<dim3(8, 64), blk, 0, stream>>>(LLH, LLL, WmHu, WmLu, lc_b,
                                                             FA, outp + 2 * NOUT, faHi, faLo, 512, 512);

    // ---- upsample (fa_hi) ----
    gemm_mfma<64,64,0,0,1><<<dim3(8, 64), blk, 0, stream>>>(faHi, w_up1, up1_b, nullptr, u1b, 512, 512);
    gemm_mfma<64,64,0,1,0><<<dim3(8, 64), blk, 0, stream>>>(u1b, w_up2, up2_b, outp + 3 * NOUT, nullptr, 512, 512);

    // ---- qkv for both TELs (merged) ----
    gemm_qkv_dual<64,128><<<dim3(12, 64, 2), blk, 0, stream>>>(faHi, faLo, w_rin, rinLoU, r_in_b, qkvR,
                                                               xHi, w_tin, t_in_b, qkvT, 1536, 512);

    // ---- dual TEL pipeline (z / row selects branch: 0=r, 1=t) ----
    attn_dual_kernel<<<dim3(2048), blk, 0, stream>>>(qkvR, qkvT, aoR, aoT);
    gemm_dual<64,64,0,0><<<dim3(8, 64, 2), blk, 0, stream>>>(aoR, aoT, w_rout, w_tout,
                                                             r_out_b, t_out_b, oR, oT,
                                                             nullptr, nullptr, 512, 512);
    add_ln_d1<<<dim3(8192), blk, 0, stream>>>(FA, oR, r_ln1_w, r_ln1_b, x1rH, x1rL,
                                              x,  oT, t_ln1_w, t_ln1_b, x1tH, x1tL);
    gemm_dual<64,128,1,1><<<dim3(16, 64, 2), blk, 0, stream>>>(x1rH, x1tH, w_rl1, w_tl1,
                                                               r_lin1_b, t_lin1_b, nullptr, nullptr,
                                                               f1R, f1T, 2048, 512);
    gemm_dual<64,64,0,0><<<dim3(8, 64, 2), blk, 0, stream>>>(f1R, f1T, w_rl2, w_tl2,
                                                             r_lin2_b, t_lin2_b, yR, yT,
                                                             nullptr, nullptr, 512, 2048);
    add_ln_d2<<<dim3(8192), blk, 0, stream>>>(x1rH, x1rL, yR, r_ln2_w, r_ln2_b, x2R,
                                              x1tH, x1tL, yT, t_ln2_w, t_ln2_b, x2T);
    relu_bln_fused<<<dim3(128), dim3(1024), 0, stream>>>(x2R, n2_w, n2_b, x2T, n1_w, n1_b, outp);
}